// Round 9
// baseline (34915.488 us; speedup 1.0000x reference)
//
#include <hip/hip_runtime.h>
#include <math.h>

#define NPTS 8192
#define NB 2
#define KNN 20
#define ROWS (NB*NPTS)    // 16384
#define NSPLIT 16         // candidate-range splits per row (knn64)
#define CPS (NPTS/NSPLIT) // 512 candidates per scanner
#define KEEP 16           // approx top-KEEP per (row,split); P(overflow into NC=32) ~1e-12
#define NC 32             // survivors refined with exact np keys
#define TILE 64           // candidates staged per LDS tile
#define JB 8              // candidates accumulated concurrently (acc registers)

// Reference-replication rules (np/XLA fp32), used ONLY in knn0 + select refine:
//   inner[n,m] = sequential-c FMA chain (first term = rounded mul)
//   sq[n]      = sequential-c adds of ROUNDED squares (no FMA)
//   key        = (2.0f*inner - sq_n) - sq_m, all fp32
//   top-20     = stable (value desc, index asc)

__device__ __forceinline__ unsigned long long shfl_xor_u64(unsigned long long v, int m) {
  unsigned lo = (unsigned)__shfl_xor((int)(unsigned)(v & 0xFFFFFFFFull), m, 64);
  unsigned hi = (unsigned)__shfl_xor((int)(unsigned)(v >> 32), m, 64);
  return ((unsigned long long)hi << 32) | (unsigned long long)lo;
}

// map neg_d (fp32) to u64 so ascending u64 == (neg_d descending, idx ascending)
__device__ __forceinline__ unsigned long long packkey(float negd, int m) {
  unsigned nb = __float_as_uint(negd) ^ 0x80000000u;            // exact negation
  nb = (nb & 0x80000000u) ? ~nb : (nb | 0x80000000u);           // monotone asc map
  return ((unsigned long long)nb << 32) | (unsigned)m;
}

// u32 sortable: ascending u32 == negd descending (ties later resolved by idx)
__device__ __forceinline__ unsigned sortdesc32(float negd) {
  unsigned s = __float_as_uint(negd);
  s = (s & 0x80000000u) ? (s ^ 0xFFFFFFFFu) : (s | 0x80000000u); // asc in negd
  return ~s;                                                      // desc in negd
}

// ---------------- prep ----------------

__global__ void prep_w0_kernel(const float* __restrict__ cw0, float* __restrict__ Wt0) {
  const int tid = threadIdx.x;                 // 384 threads
  const int c = tid >> 6, o = tid & 63;
  if (tid < 384) Wt0[c*64 + o] = cw0[o*6 + c];
}

__global__ void prep_wc_kernel(const float* __restrict__ cws, float* __restrict__ Wt) {
  const int f = blockIdx.x*256 + threadIdx.x;  // < 3*8192
  const int i = f >> 13, r = f & 8191, c = r >> 6, o = r & 63;
  Wt[f] = cws[i*8192 + o*128 + c];
}

__global__ void prep_fw_kernel(const float* __restrict__ fws, float* __restrict__ fwt) {
  const int f = blockIdx.x*256 + threadIdx.x;  // < 3*8192
  const int i = f >> 13, r = f & 8191, c = r >> 6, o = r & 63;
  fwt[f] = fws[i*8192 + o*128 + c];
}

__global__ void prep_x_kernel(const float* __restrict__ x,
                              float* __restrict__ xt, float* __restrict__ xnorm) {
#pragma clang fp contract(off)
  const int t = blockIdx.x*256 + threadIdx.x;  // < ROWS
  const int b = t >> 13, n = t & (NPTS-1);
  const float v0 = x[((size_t)b*3 + 0)*NPTS + n];
  const float v1 = x[((size_t)b*3 + 1)*NPTS + n];
  const float v2 = x[((size_t)b*3 + 2)*NPTS + n];
  ((float4*)xt)[t] = make_float4(v0, v1, v2, 0.f);
  float a = __fmul_rn(v0, v0);
  a = __fadd_rn(a, __fmul_rn(v1, v1));
  a = __fadd_rn(a, __fmul_rn(v2, v2));
  xnorm[t] = a;
}

// ---------------- KNN layer 0 (wave-per-row; np-exact keys directly) ----------------
__global__ __launch_bounds__(256)
void knn0_kernel(const float* __restrict__ pts, const float* __restrict__ norms,
                 int* __restrict__ idx) {
#pragma clang fp contract(off)
  const int tid = threadIdx.x;
  const int wave = tid >> 6, lane = tid & 63;
  const int row = blockIdx.x*4 + wave;
  const int b = row >> 13, n = row & (NPTS-1);
  const float4* P = ((const float4*)pts) + (size_t)b * NPTS;
  const float4 rv = P[n];
  const float* nrm = norms + (size_t)b*NPTS;
  const float nrmN = nrm[n];

  unsigned long long keys[12];
#pragma unroll
  for (int i = 0; i < 12; ++i) keys[i] = ~0ull;

  for (int t = 0; t < NPTS/64; ++t) {
    const int m = t*64 + lane;
    const float4 q = P[m];
    float acc = __fmul_rn(rv.x, q.x);      // fma(a0,b0,0) == rounded mul
    acc = fmaf(rv.y, q.y, acc);
    acc = fmaf(rv.z, q.z, acc);
    const float negd = __fsub_rn(__fsub_rn(__fmul_rn(2.0f, acc), nrmN), nrm[m]);
    unsigned long long uk = packkey(negd, m);
    if (uk < keys[11]) {
#pragma unroll
      for (int i = 0; i < 12; ++i)
        if (uk < keys[i]) { const unsigned long long tmp = keys[i]; keys[i] = uk; uk = tmp; }
    }
  }

  int stash = 0;
  unsigned long long head = keys[0];
  for (int r = 0; r < KNN; ++r) {
    unsigned long long best = head;
#pragma unroll
    for (int off = 32; off; off >>= 1) {
      const unsigned long long o = shfl_xor_u64(best, off);
      if (o < best) best = o;
    }
    if (head == best) {
#pragma unroll
      for (int i = 0; i < 11; ++i) keys[i] = keys[i+1];
      keys[11] = ~0ull;
      head = keys[0];
    }
    if (lane == r) stash = (int)(unsigned)(best & 0xFFFFFFFFull);
  }
  if (lane < KNN) idx[(size_t)row*KNN + lane] = stash;
}

// ---------------- KNN 1-3 pass 1: approx scan (LDS-staged, thread-per-row) ----------------
// Approx keys (tree fp32) are a PREFILTER only; exact np ranking happens in select.
// Register-budget design: f[16] resident (64 VGPR) + acc[JB=8] + keys/idxs (32)
// + addressing ~= 116 VGPR, under the 128 cap of 4 waves/SIMD -> no spill.
__global__ __launch_bounds__(256, 4)
void knn64_scan_kernel(const float* __restrict__ hf, const float* __restrict__ norms,
                       unsigned long long* __restrict__ cand) {
  __shared__ float4 tq[TILE*16];   // 64 cands x 64 ch = 16 KB
  __shared__ float tnrm[TILE];
  const int tid = threadIdx.x;
  const int rb = blockIdx.x >> 4, cs = blockIdx.x & (NSPLIT-1);
  const int row = rb*256 + tid;          // 256 consecutive rows; same batch
  const int b = row >> 13;
  const int csBase = cs*CPS;

  float4 f[16];
  const float4* Pf = ((const float4*)hf) + (size_t)row*16;
#pragma unroll
  for (int i = 0; i < 16; ++i) f[i] = Pf[i];
  const float nrmN = norms[row];
  const float* nrmC = norms + (size_t)b*NPTS + csBase;
  const float4* Pc4 = ((const float4*)hf) + ((size_t)b*NPTS + csBase)*16;

  unsigned keys[KEEP], idxs[KEEP];
#pragma unroll
  for (int i = 0; i < KEEP; ++i) { keys[i] = 0xFFFFFFFFu; idxs[i] = 0xFFFFFFFFu; }

  for (int t = 0; t < CPS/TILE; ++t) {
    // stage 64 cands x 64 ch: 1024 float4, coalesced 4/thread
#pragma unroll
    for (int j = 0; j < (TILE*16)/256; ++j)
      tq[tid + j*256] = Pc4[(size_t)t*(TILE*16) + tid + j*256];
    if (tid < TILE) tnrm[tid] = nrmC[t*TILE + tid];
    __syncthreads();

    for (int jb = 0; jb < TILE/JB; ++jb) {
      float acc[JB];
#pragma unroll
      for (int q = 0; q < JB; ++q) acc[q] = 0.f;
#pragma unroll
      for (int c4 = 0; c4 < 16; ++c4) {
        const float4 f4 = f[c4];
#pragma unroll
        for (int q = 0; q < JB; ++q) {
          const float4 qv = tq[(jb*JB + q)*16 + c4];   // broadcast ds_read_b128
          acc[q] = fmaf(f4.x, qv.x, acc[q]);
          acc[q] = fmaf(f4.y, qv.y, acc[q]);
          acc[q] = fmaf(f4.z, qv.z, acc[q]);
          acc[q] = fmaf(f4.w, qv.w, acc[q]);
        }
      }
#pragma unroll
      for (int q = 0; q < JB; ++q) {
        const int jj = jb*JB + q;
        const float negd = 2.0f*acc[q] - nrmN - tnrm[jj];
        const unsigned kd = sortdesc32(negd);
        if (kd < keys[KEEP-1]) {
          unsigned ck = kd, ci = (unsigned)(csBase + t*TILE + jj);
#pragma unroll
          for (int i = 0; i < KEEP; ++i) {
            const bool sh = (kd < keys[i]);   // vs ORIGINAL kd: ties keep idx-asc
            const unsigned tk = keys[i], ti = idxs[i];
            keys[i] = sh ? ck : tk;  idxs[i] = sh ? ci : ti;
            ck      = sh ? tk : ck;  ci      = sh ? ti : ci;
          }
        }
      }
    }
    __syncthreads();
  }

  unsigned long long* o = cand + ((size_t)row*NSPLIT + cs)*KEEP;
#pragma unroll
  for (int i = 0; i < KEEP; ++i)
    o[i] = ((unsigned long long)keys[i] << 32) | idxs[i];   // ascending (sorted)
}

// ---------------- KNN 1-3 pass 2: merge 256 -> top-32 approx -> np-exact top-20 ----------------
__global__ __launch_bounds__(256)
void knn64_select_kernel(const float* __restrict__ hf, const float* __restrict__ norms,
                         const unsigned long long* __restrict__ cand,
                         int* __restrict__ idx) {
#pragma clang fp contract(off)
  const int tid = threadIdx.x, wave = tid >> 6, lane = tid & 63;
  const int row = blockIdx.x*4 + wave;
  const int b = row >> 13;
  const unsigned long long* cr = cand + (size_t)row*(NSPLIT*KEEP);
  // lane holds 4 keys of one split-quarter: 16%4==0 -> within-split ascending
  unsigned long long a0 = cr[lane*4 + 0];
  unsigned long long a1 = cr[lane*4 + 1];
  unsigned long long a2 = cr[lane*4 + 2];
  unsigned long long a3 = cr[lane*4 + 3];

  int cidx = 0;
  for (int r = 0; r < NC; ++r) {
    unsigned long long best = a0;
#pragma unroll
    for (int off = 32; off; off >>= 1) {
      const unsigned long long o = shfl_xor_u64(best, off);
      if (o < best) best = o;
    }
    if (a0 == best) { a0 = a1; a1 = a2; a2 = a3; a3 = ~0ull; }
    if (lane == r) cidx = (int)(unsigned)(best & 0xFFFFFFFFull);
  }

  // np-exact key for the NC survivors (lane r holds candidate r)
  unsigned long long uk = ~0ull;
  if (lane < NC) {
    const float4* Pr = ((const float4*)hf) + (size_t)row*16;           // uniform
    const float4* Pc = ((const float4*)hf) + ((size_t)b*NPTS + cidx)*16;
    float4 fr = Pr[0], qc = Pc[0];
    float acc = __fmul_rn(fr.x, qc.x);
    acc = fmaf(fr.y, qc.y, acc);
    acc = fmaf(fr.z, qc.z, acc);
    acc = fmaf(fr.w, qc.w, acc);
#pragma unroll
    for (int i = 1; i < 16; ++i) {
      fr = Pr[i]; qc = Pc[i];
      acc = fmaf(fr.x, qc.x, acc);
      acc = fmaf(fr.y, qc.y, acc);
      acc = fmaf(fr.z, qc.z, acc);
      acc = fmaf(fr.w, qc.w, acc);
    }
    const float negd = __fsub_rn(__fsub_rn(__fmul_rn(2.0f, acc), norms[row]),
                                 norms[(size_t)b*NPTS + cidx]);
    uk = packkey(negd, cidx);
  }

  int stash = 0;
  for (int r = 0; r < KNN; ++r) {
    unsigned long long best = uk;
#pragma unroll
    for (int off = 32; off; off >>= 1) {
      const unsigned long long o = shfl_xor_u64(best, off);
      if (o < best) best = o;
    }
    if (lane == r) stash = (int)(unsigned)(best & 0xFFFFFFFFull);
    if (uk == best) uk = ~0ull;   // unique keys: exactly one lane retires
  }
  if (lane < KNN) idx[(size_t)row*KNN + lane] = stash;
}

// ---------------- conv layer 0: literal per-neighbor conv, BN, lrelu, max ----------------
__global__ __launch_bounds__(256)
void conv0_kernel(const int* __restrict__ idx, const float* __restrict__ xt,
                  const float* __restrict__ Wt0, const float* __restrict__ gam,
                  const float* __restrict__ bet, const float* __restrict__ rmn,
                  const float* __restrict__ rvr,
                  float* __restrict__ outc, float* __restrict__ hpm) {
#pragma clang fp contract(off)
  const int tid = threadIdx.x, wave = tid >> 6, lane = tid & 63;
  const int row = blockIdx.x*4 + wave;
  const int b = row >> 13, n = row & (NPTS-1);
  const float4* P = ((const float4*)xt) + (size_t)b * NPTS;
  const float4 ctr = P[n];
  float wv[6];
#pragma unroll
  for (int c = 0; c < 6; ++c) wv[c] = Wt0[c*64 + lane];
  const float sc = __fdiv_rn(gam[lane], sqrtf(__fadd_rn(rvr[lane], 1e-5f)));
  const float mn = rmn[lane], bt = bet[lane];

  float mx = -3.0e38f;
  const int* ip = idx + (size_t)row*KNN;
  for (int k = 0; k < KNN; ++k) {
    const float4 q = P[ip[k]];
    float acc = __fmul_rn(wv[0], __fsub_rn(q.x, ctr.x));
    acc = __fadd_rn(acc, __fmul_rn(wv[1], __fsub_rn(q.y, ctr.y)));
    acc = __fadd_rn(acc, __fmul_rn(wv[2], __fsub_rn(q.z, ctr.z)));
    acc = __fadd_rn(acc, __fmul_rn(wv[3], ctr.x));
    acc = __fadd_rn(acc, __fmul_rn(wv[4], ctr.y));
    acc = __fadd_rn(acc, __fmul_rn(wv[5], ctr.z));
    float y = __fadd_rn(__fmul_rn(__fsub_rn(acc, mn), sc), bt);
    y = (y >= 0.f) ? y : __fmul_rn(0.2f, y);
    mx = fmaxf(mx, y);
  }
  outc[((size_t)(b*64 + lane))*NPTS + n] = mx;
  hpm[(size_t)row*64 + lane] = mx;
}

// ---------------- conv layers 1-3: literal per-neighbor conv (128-ch), BN, lrelu, max ----------------
__global__ __launch_bounds__(256)
void convL_kernel(const int* __restrict__ idx, const float* __restrict__ hf,
                  const float* __restrict__ WtL, const float* __restrict__ gam,
                  const float* __restrict__ bet, const float* __restrict__ rmn,
                  const float* __restrict__ rvr, const int L,
                  float* __restrict__ outc, float* __restrict__ hpm) {
#pragma clang fp contract(off)
  __shared__ float ls[21*64];          // row 0 = ctr, rows 1..20 = neighbors
  __shared__ float pmax[4*64];
  const int tid = threadIdx.x, wave = tid >> 6, lane = tid & 63;
  const int row = blockIdx.x;
  const int b = row >> 13, n = row & (NPTS-1);
  const int* ip = idx + (size_t)row*KNN;
#pragma unroll
  for (int j = 0; j < 6; ++j) {
    const int r = j*4 + wave;
    if (r < 21) {
      const int src = (r == 0) ? row : (b*NPTS + ip[r-1]);
      ls[r*64 + lane] = hf[(size_t)src*64 + lane];
    }
  }
  __syncthreads();

  float wv[128];
#pragma unroll
  for (int c = 0; c < 128; ++c) wv[c] = WtL[c*64 + lane];
  const float sc = __fdiv_rn(gam[L*64 + lane], sqrtf(__fadd_rn(rvr[L*64 + lane], 1e-5f)));
  const float mn = rmn[L*64 + lane], bt = bet[L*64 + lane];

  float mx = -3.0e38f;
  for (int j = 0; j < 5; ++j) {
    const int k = wave*5 + j;
    const float* nb = &ls[(1+k)*64];
    float acc = __fmul_rn(wv[0], __fsub_rn(nb[0], ls[0]));
#pragma unroll
    for (int c = 1; c < 64; ++c)
      acc = __fadd_rn(acc, __fmul_rn(wv[c], __fsub_rn(nb[c], ls[c])));
#pragma unroll
    for (int c = 64; c < 128; ++c)
      acc = __fadd_rn(acc, __fmul_rn(wv[c], ls[c-64]));
    float y = __fadd_rn(__fmul_rn(__fsub_rn(acc, mn), sc), bt);
    y = (y >= 0.f) ? y : __fmul_rn(0.2f, y);
    mx = fmaxf(mx, y);
  }
  pmax[wave*64 + lane] = mx;
  __syncthreads();
  if (tid < 64) {
    const float m01 = fmaxf(pmax[tid], pmax[64 + tid]);
    const float m23 = fmaxf(pmax[128 + tid], pmax[192 + tid]);
    const float m = fmaxf(m01, m23);
    outc[((size_t)(b*64 + tid))*NPTS + n] = m;
    hpm[(size_t)row*64 + tid] = m;
  }
}

// ---------------- fuse: hf = elu(fw . [h; reps]); + hnorm (seq sum of rounded squares) ----------------
__global__ __launch_bounds__(256)
void fuse_kernel(const float* __restrict__ hpm, const float* __restrict__ repsL,
                 const float* __restrict__ fwtL, float* __restrict__ hf,
                 float* __restrict__ hnorm) {
#pragma clang fp contract(off)
  __shared__ float cs[32*130];   // 32 points x 128 channels (+2 pad)
  __shared__ float yb[32*65];    // fused outputs for the sq pass
  const int tid = threadIdx.x, wave = tid >> 6, lane = tid & 63;
  const size_t rowbase = (size_t)blockIdx.x*32;          // b*N + n0
  const int b = (int)(rowbase >> 13);
  const int n0 = (int)(rowbase & (NPTS-1));
#pragma unroll
  for (int j = 0; j < 8; ++j) {
    const int p = j*4 + wave;
    cs[p*130 + lane] = hpm[(rowbase + p)*64 + lane];
  }
  const float* rb = repsL + (size_t)b*64*NPTS;
  const int pl = lane & 31;
#pragma unroll
  for (int j = 0; j < 8; ++j) {
    const int c = j*8 + wave*2 + (lane >> 5);
    cs[pl*130 + 64 + c] = rb[(size_t)c*NPTS + n0 + pl];
  }
  __syncthreads();
  float wv[128];
#pragma unroll
  for (int c = 0; c < 128; ++c) wv[c] = fwtL[c*64 + lane];
  for (int pp = 0; pp < 8; ++pp) {
    const int p = wave*8 + pp;
    float acc = __fmul_rn(wv[0], cs[p*130]);
#pragma unroll
    for (int c = 1; c < 128; ++c)
      acc = __fadd_rn(acc, __fmul_rn(wv[c], cs[p*130 + c]));
    const float y = (acc > 0.f) ? acc : (float)expm1((double)acc);  // jax.nn.elu
    hf[(rowbase + p)*64 + lane] = y;
    yb[p*65 + lane] = y;
  }
  __syncthreads();
  if (tid < 32) {
    float a = __fmul_rn(yb[tid*65], yb[tid*65]);
#pragma unroll
    for (int c = 1; c < 64; ++c) {
      const float t = yb[tid*65 + c];
      a = __fadd_rn(a, __fmul_rn(t, t));
    }
    hnorm[rowbase + tid] = a;
  }
}

// ---------------- launch ----------------
extern "C" void kernel_launch(void* const* d_in, const int* in_sizes, int n_in,
                              void* d_out, int out_size, void* d_ws, size_t ws_size,
                              hipStream_t stream) {
  const float* x    = (const float*)d_in[0];
  const float* reps = (const float*)d_in[1];
  const float* cw0  = (const float*)d_in[2];
  const float* cws  = (const float*)d_in[3];
  const float* gam  = (const float*)d_in[4];
  const float* bet  = (const float*)d_in[5];
  const float* rmn  = (const float*)d_in[6];
  const float* rvr  = (const float*)d_in[7];
  const float* fws  = (const float*)d_in[8];
  float* out = (float*)d_out;

  unsigned long long* cand = (unsigned long long*)d_ws;  // ROWS*16*16 u64 = 33.6MB
  int* idx = (int*)(cand + (size_t)ROWS*NSPLIT*KEEP);
  float* w = (float*)(idx + (size_t)ROWS*KNN);
  float* xt    = w;  w += (size_t)ROWS*4;
  float* xnorm = w;  w += ROWS;
  float* hf    = w;  w += (size_t)ROWS*64;
  float* hnorm = w;  w += ROWS;
  float* hpm   = w;  w += (size_t)ROWS*64;
  float* Wt0   = w;  w += 8*64;
  float* Wt    = w;  w += 3*128*64;
  float* fwt   = w;  w += 3*128*64;

  hipLaunchKernelGGL(prep_w0_kernel, dim3(1),   dim3(384), 0, stream, cw0, Wt0);
  hipLaunchKernelGGL(prep_wc_kernel, dim3(96),  dim3(256), 0, stream, cws, Wt);
  hipLaunchKernelGGL(prep_fw_kernel, dim3(96),  dim3(256), 0, stream, fws, fwt);
  hipLaunchKernelGGL(prep_x_kernel,  dim3(ROWS/256), dim3(256), 0, stream, x, xt, xnorm);

  const size_t chunk = (size_t)NB*64*NPTS;

  // layer 0
  hipLaunchKernelGGL(knn0_kernel,  dim3(ROWS/4), dim3(256), 0, stream, xt, xnorm, idx);
  hipLaunchKernelGGL(conv0_kernel, dim3(ROWS/4), dim3(256), 0, stream,
                     idx, xt, Wt0, gam, bet, rmn, rvr, out, hpm);

  for (int i = 0; i < 3; ++i) {
    hipLaunchKernelGGL(fuse_kernel, dim3(ROWS/32), dim3(256), 0, stream,
                       hpm, reps + (size_t)i*NB*64*NPTS, fwt + (size_t)i*8192, hf, hnorm);
    hipLaunchKernelGGL(knn64_scan_kernel,  dim3((ROWS/256)*NSPLIT), dim3(256), 0, stream,
                       hf, hnorm, cand);
    hipLaunchKernelGGL(knn64_select_kernel, dim3(ROWS/4), dim3(256), 0, stream,
                       hf, hnorm, cand, idx);
    hipLaunchKernelGGL(convL_kernel, dim3(ROWS), dim3(256), 0, stream,
                       idx, hf, Wt + (size_t)i*8192, gam, bet, rmn, rvr, i + 1,
                       out + (size_t)(i+1)*chunk, hpm);
  }
}

// Round 11
// 3072.036 us; speedup vs baseline: 11.3656x; 11.3656x over previous
//
#include <hip/hip_runtime.h>
#include <math.h>

#define NPTS 8192
#define NB 2
#define KNN 20
#define ROWS (NB*NPTS)    // 16384
#define NSPLIT 16         // candidate-range splits per row (knn64)
#define CPS (NPTS/NSPLIT) // 512 candidates per scanner
#define KEEP 16           // approx top-KEEP per (row,split)
#define NC 32             // survivors refined with exact np keys
#define TILE 128          // candidates staged per LDS tile (f16: 16 KB)

typedef _Float16 half2v __attribute__((ext_vector_type(2)));

// Reference-replication rules (np/XLA fp32), used ONLY in knn0 + select refine:
//   inner[n,m] = sequential-c FMA chain (first term = rounded mul)
//   sq[n]      = sequential-c adds of ROUNDED squares (no FMA)
//   key        = (2.0f*inner - sq_n) - sq_m, all fp32
//   top-20     = stable (value desc, index asc)

__device__ __forceinline__ unsigned long long shfl_xor_u64(unsigned long long v, int m) {
  unsigned lo = (unsigned)__shfl_xor((int)(unsigned)(v & 0xFFFFFFFFull), m, 64);
  unsigned hi = (unsigned)__shfl_xor((int)(unsigned)(v >> 32), m, 64);
  return ((unsigned long long)hi << 32) | (unsigned long long)lo;
}

__device__ __forceinline__ unsigned long long packkey(float negd, int m) {
  unsigned nb = __float_as_uint(negd) ^ 0x80000000u;            // exact negation
  nb = (nb & 0x80000000u) ? ~nb : (nb | 0x80000000u);           // monotone asc map
  return ((unsigned long long)nb << 32) | (unsigned)m;
}

// u32 sortable: ascending u32 == negd descending
__device__ __forceinline__ unsigned sortdesc32(float negd) {
  unsigned s = __float_as_uint(negd);
  s = (s & 0x80000000u) ? (s ^ 0xFFFFFFFFu) : (s | 0x80000000u);
  return ~s;
}

__device__ __forceinline__ half2v u2h(unsigned u) {
  half2v h;
  __builtin_memcpy(&h, &u, 4);
  return h;
}
__device__ __forceinline__ unsigned pk16(float a, float b) {
  const auto h = __builtin_amdgcn_cvt_pkrtz(a, b);   // v2 fp16, RTZ
  unsigned u;
  __builtin_memcpy(&u, &h, 4);
  return u;
}

// ---------------- prep ----------------

__global__ void prep_w0_kernel(const float* __restrict__ cw0, float* __restrict__ Wt0) {
  const int tid = threadIdx.x;                 // 384 threads
  const int c = tid >> 6, o = tid & 63;
  if (tid < 384) Wt0[c*64 + o] = cw0[o*6 + c];
}

__global__ void prep_wc_kernel(const float* __restrict__ cws, float* __restrict__ Wt) {
  const int f = blockIdx.x*256 + threadIdx.x;  // < 3*8192
  const int i = f >> 13, r = f & 8191, c = r >> 6, o = r & 63;
  Wt[f] = cws[i*8192 + o*128 + c];
}

__global__ void prep_fw_kernel(const float* __restrict__ fws, float* __restrict__ fwt) {
  const int f = blockIdx.x*256 + threadIdx.x;  // < 3*8192
  const int i = f >> 13, r = f & 8191, c = r >> 6, o = r & 63;
  fwt[f] = fws[i*8192 + o*128 + c];
}

__global__ void prep_x_kernel(const float* __restrict__ x,
                              float* __restrict__ xt, float* __restrict__ xnorm) {
#pragma clang fp contract(off)
  const int t = blockIdx.x*256 + threadIdx.x;  // < ROWS
  const int b = t >> 13, n = t & (NPTS-1);
  const float v0 = x[((size_t)b*3 + 0)*NPTS + n];
  const float v1 = x[((size_t)b*3 + 1)*NPTS + n];
  const float v2 = x[((size_t)b*3 + 2)*NPTS + n];
  ((float4*)xt)[t] = make_float4(v0, v1, v2, 0.f);
  float a = __fmul_rn(v0, v0);
  a = __fadd_rn(a, __fmul_rn(v1, v1));
  a = __fadd_rn(a, __fmul_rn(v2, v2));
  xnorm[t] = a;
}

// ---------------- KNN layer 0 (wave-per-row; np-exact keys directly) ----------------
__global__ __launch_bounds__(256)
void knn0_kernel(const float* __restrict__ pts, const float* __restrict__ norms,
                 int* __restrict__ idx) {
#pragma clang fp contract(off)
  const int tid = threadIdx.x;
  const int wave = tid >> 6, lane = tid & 63;
  const int row = blockIdx.x*4 + wave;
  const int b = row >> 13, n = row & (NPTS-1);
  const float4* P = ((const float4*)pts) + (size_t)b * NPTS;
  const float4 rv = P[n];
  const float* nrm = norms + (size_t)b*NPTS;
  const float nrmN = nrm[n];

  unsigned long long keys[12];
#pragma unroll
  for (int i = 0; i < 12; ++i) keys[i] = ~0ull;

  for (int t = 0; t < NPTS/64; ++t) {
    const int m = t*64 + lane;
    const float4 q = P[m];
    float acc = __fmul_rn(rv.x, q.x);      // fma(a0,b0,0) == rounded mul
    acc = fmaf(rv.y, q.y, acc);
    acc = fmaf(rv.z, q.z, acc);
    const float negd = __fsub_rn(__fsub_rn(__fmul_rn(2.0f, acc), nrmN), nrm[m]);
    unsigned long long uk = packkey(negd, m);
    if (uk < keys[11]) {
#pragma unroll
      for (int i = 0; i < 12; ++i)
        if (uk < keys[i]) { const unsigned long long tmp = keys[i]; keys[i] = uk; uk = tmp; }
    }
  }

  int stash = 0;
  unsigned long long head = keys[0];
  for (int r = 0; r < KNN; ++r) {
    unsigned long long best = head;
#pragma unroll
    for (int off = 32; off; off >>= 1) {
      const unsigned long long o = shfl_xor_u64(best, off);
      if (o < best) best = o;
    }
    if (head == best) {
#pragma unroll
      for (int i = 0; i < 11; ++i) keys[i] = keys[i+1];
      keys[11] = ~0ull;
      head = keys[0];
    }
    if (lane == r) stash = (int)(unsigned)(best & 0xFFFFFFFFull);
  }
  if (lane < KNN) idx[(size_t)row*KNN + lane] = stash;
}

// ---------------- KNN 1-3 pass 1: fp16-dot2 approx scan (LDS-staged) ----------------
// Prefilter only; exact np ranking happens in select. fp16 key err ~0.005-0.03
// << d20->d32 margin; NC=32 refine absorbs it.
__global__ __launch_bounds__(256, 2)
void knn64_scan_kernel(const uint4* __restrict__ hf16, const float* __restrict__ norms,
                       unsigned long long* __restrict__ cand) {
  __shared__ uint4 tq[TILE*8];     // 128 cands x 64ch f16 = 1024 uint4 = 16 KB
  __shared__ float tnrm[TILE];
  const int tid = threadIdx.x;
  const int rb = blockIdx.x >> 4, cs = blockIdx.x & (NSPLIT-1);
  const int row = rb*256 + tid;          // 256 consecutive rows; same batch
  const int b = row >> 13;
  const int csBase = cs*CPS;

  // row features: 64 ch f16 = 8 uint4 = 32 half2 (32 VGPRs)
  half2v f2[32];
  {
    const uint4* Pf = hf16 + (size_t)row*8;
#pragma unroll
    for (int u = 0; u < 8; ++u) {
      const uint4 q = Pf[u];
      f2[u*4+0] = u2h(q.x); f2[u*4+1] = u2h(q.y);
      f2[u*4+2] = u2h(q.z); f2[u*4+3] = u2h(q.w);
    }
  }
  const float nrmN = norms[row];
  const float* nrmC = norms + (size_t)b*NPTS + csBase;
  const uint4* Pc = hf16 + ((size_t)b*NPTS + csBase)*8;

  unsigned keys[KEEP], idxs[KEEP];
#pragma unroll
  for (int i = 0; i < KEEP; ++i) { keys[i] = 0xFFFFFFFFu; idxs[i] = 0xFFFFFFFFu; }

  for (int t = 0; t < CPS/TILE; ++t) {
    // stage 128 cands x 128 B = 1024 uint4, coalesced 4/thread
#pragma unroll
    for (int j = 0; j < 4; ++j)
      tq[tid + j*256] = Pc[(size_t)t*(TILE*8) + tid + j*256];
    if (tid < TILE) tnrm[tid] = nrmC[t*TILE + tid];
    __syncthreads();

    for (int jj = 0; jj < TILE; ++jj) {
      const uint4* qp = &tq[jj*8];   // wave-uniform -> broadcast ds_read_b128
      float a0 = 0.f, a1 = 0.f, a2 = 0.f, a3 = 0.f;
#pragma unroll
      for (int u = 0; u < 8; ++u) {
        const uint4 q = qp[u];
        a0 = __builtin_amdgcn_fdot2(f2[u*4+0], u2h(q.x), a0, false);
        a1 = __builtin_amdgcn_fdot2(f2[u*4+1], u2h(q.y), a1, false);
        a2 = __builtin_amdgcn_fdot2(f2[u*4+2], u2h(q.z), a2, false);
        a3 = __builtin_amdgcn_fdot2(f2[u*4+3], u2h(q.w), a3, false);
      }
      const float inner = (a0 + a1) + (a2 + a3);
      const float negd = 2.0f*inner - nrmN - tnrm[jj];
      const unsigned kd = sortdesc32(negd);
      if (kd < keys[KEEP-1]) {
        unsigned ck = kd, ci = (unsigned)(csBase + t*TILE + jj);
#pragma unroll
        for (int i = 0; i < KEEP; ++i) {
          const bool sh = (kd < keys[i]);   // vs ORIGINAL kd: ties keep idx-asc
          const unsigned tk = keys[i], ti = idxs[i];
          keys[i] = sh ? ck : tk;  idxs[i] = sh ? ci : ti;
          ck      = sh ? tk : ck;  ci      = sh ? ti : ci;
        }
      }
    }
    __syncthreads();
  }

  unsigned long long* o = cand + ((size_t)row*NSPLIT + cs)*KEEP;
#pragma unroll
  for (int i = 0; i < KEEP; ++i)
    o[i] = ((unsigned long long)keys[i] << 32) | idxs[i];   // ascending (sorted)
}

// ---------------- KNN 1-3 pass 2: merge 256 -> top-32 approx -> np-exact top-20 ----------------
__global__ __launch_bounds__(256)
void knn64_select_kernel(const float* __restrict__ hf, const float* __restrict__ norms,
                         const unsigned long long* __restrict__ cand,
                         int* __restrict__ idx) {
#pragma clang fp contract(off)
  const int tid = threadIdx.x, wave = tid >> 6, lane = tid & 63;
  const int row = blockIdx.x*4 + wave;
  const int b = row >> 13;
  const unsigned long long* cr = cand + (size_t)row*(NSPLIT*KEEP);
  // lane holds 4 keys of one split-quarter: 16%4==0 -> within-split ascending
  unsigned long long a0 = cr[lane*4 + 0];
  unsigned long long a1 = cr[lane*4 + 1];
  unsigned long long a2 = cr[lane*4 + 2];
  unsigned long long a3 = cr[lane*4 + 3];

  int cidx = 0;
  for (int r = 0; r < NC; ++r) {
    unsigned long long best = a0;
#pragma unroll
    for (int off = 32; off; off >>= 1) {
      const unsigned long long o = shfl_xor_u64(best, off);
      if (o < best) best = o;
    }
    if (a0 == best) { a0 = a1; a1 = a2; a2 = a3; a3 = ~0ull; }
    if (lane == r) cidx = (int)(unsigned)(best & 0xFFFFFFFFull);
  }

  // np-exact key for the NC survivors (lane r holds candidate r)
  unsigned long long uk = ~0ull;
  if (lane < NC) {
    const float4* Pr = ((const float4*)hf) + (size_t)row*16;
    const float4* Pc = ((const float4*)hf) + ((size_t)b*NPTS + cidx)*16;
    float4 fr = Pr[0], qc = Pc[0];
    float acc = __fmul_rn(fr.x, qc.x);
    acc = fmaf(fr.y, qc.y, acc);
    acc = fmaf(fr.z, qc.z, acc);
    acc = fmaf(fr.w, qc.w, acc);
#pragma unroll
    for (int i = 1; i < 16; ++i) {
      fr = Pr[i]; qc = Pc[i];
      acc = fmaf(fr.x, qc.x, acc);
      acc = fmaf(fr.y, qc.y, acc);
      acc = fmaf(fr.z, qc.z, acc);
      acc = fmaf(fr.w, qc.w, acc);
    }
    const float negd = __fsub_rn(__fsub_rn(__fmul_rn(2.0f, acc), norms[row]),
                                 norms[(size_t)b*NPTS + cidx]);
    uk = packkey(negd, cidx);
  }

  int stash = 0;
  for (int r = 0; r < KNN; ++r) {
    unsigned long long best = uk;
#pragma unroll
    for (int off = 32; off; off >>= 1) {
      const unsigned long long o = shfl_xor_u64(best, off);
      if (o < best) best = o;
    }
    if (lane == r) stash = (int)(unsigned)(best & 0xFFFFFFFFull);
    if (uk == best) uk = ~0ull;   // unique keys: exactly one lane retires
  }
  if (lane < KNN) idx[(size_t)row*KNN + lane] = stash;
}

// ---------------- conv layer 0 ----------------
__global__ __launch_bounds__(256)
void conv0_kernel(const int* __restrict__ idx, const float* __restrict__ xt,
                  const float* __restrict__ Wt0, const float* __restrict__ gam,
                  const float* __restrict__ bet, const float* __restrict__ rmn,
                  const float* __restrict__ rvr,
                  float* __restrict__ outc, float* __restrict__ hpm) {
#pragma clang fp contract(off)
  const int tid = threadIdx.x, wave = tid >> 6, lane = tid & 63;
  const int row = blockIdx.x*4 + wave;
  const int b = row >> 13, n = row & (NPTS-1);
  const float4* P = ((const float4*)xt) + (size_t)b * NPTS;
  const float4 ctr = P[n];
  float wv[6];
#pragma unroll
  for (int c = 0; c < 6; ++c) wv[c] = Wt0[c*64 + lane];
  const float sc = __fdiv_rn(gam[lane], sqrtf(__fadd_rn(rvr[lane], 1e-5f)));
  const float mn = rmn[lane], bt = bet[lane];

  float mx = -3.0e38f;
  const int* ip = idx + (size_t)row*KNN;
  for (int k = 0; k < KNN; ++k) {
    const float4 q = P[ip[k]];
    float acc = __fmul_rn(wv[0], __fsub_rn(q.x, ctr.x));
    acc = __fadd_rn(acc, __fmul_rn(wv[1], __fsub_rn(q.y, ctr.y)));
    acc = __fadd_rn(acc, __fmul_rn(wv[2], __fsub_rn(q.z, ctr.z)));
    acc = __fadd_rn(acc, __fmul_rn(wv[3], ctr.x));
    acc = __fadd_rn(acc, __fmul_rn(wv[4], ctr.y));
    acc = __fadd_rn(acc, __fmul_rn(wv[5], ctr.z));
    float y = __fadd_rn(__fmul_rn(__fsub_rn(acc, mn), sc), bt);
    y = (y >= 0.f) ? y : __fmul_rn(0.2f, y);
    mx = fmaxf(mx, y);
  }
  outc[((size_t)(b*64 + lane))*NPTS + n] = mx;
  hpm[(size_t)row*64 + lane] = mx;
}

// ---------------- conv layers 1-3 ----------------
__global__ __launch_bounds__(256)
void convL_kernel(const int* __restrict__ idx, const float* __restrict__ hf,
                  const float* __restrict__ WtL, const float* __restrict__ gam,
                  const float* __restrict__ bet, const float* __restrict__ rmn,
                  const float* __restrict__ rvr, const int L,
                  float* __restrict__ outc, float* __restrict__ hpm) {
#pragma clang fp contract(off)
  __shared__ float ls[21*64];          // row 0 = ctr, rows 1..20 = neighbors
  __shared__ float pmax[4*64];
  const int tid = threadIdx.x, wave = tid >> 6, lane = tid & 63;
  const int row = blockIdx.x;
  const int b = row >> 13, n = row & (NPTS-1);
  const int* ip = idx + (size_t)row*KNN;
#pragma unroll
  for (int j = 0; j < 6; ++j) {
    const int r = j*4 + wave;
    if (r < 21) {
      const int src = (r == 0) ? row : (b*NPTS + ip[r-1]);
      ls[r*64 + lane] = hf[(size_t)src*64 + lane];
    }
  }
  __syncthreads();

  float wv[128];
#pragma unroll
  for (int c = 0; c < 128; ++c) wv[c] = WtL[c*64 + lane];
  const float sc = __fdiv_rn(gam[L*64 + lane], sqrtf(__fadd_rn(rvr[L*64 + lane], 1e-5f)));
  const float mn = rmn[L*64 + lane], bt = bet[L*64 + lane];

  float mx = -3.0e38f;
  for (int j = 0; j < 5; ++j) {
    const int k = wave*5 + j;
    const float* nb = &ls[(1+k)*64];
    float acc = __fmul_rn(wv[0], __fsub_rn(nb[0], ls[0]));
#pragma unroll
    for (int c = 1; c < 64; ++c)
      acc = __fadd_rn(acc, __fmul_rn(wv[c], __fsub_rn(nb[c], ls[c])));
#pragma unroll
    for (int c = 64; c < 128; ++c)
      acc = __fadd_rn(acc, __fmul_rn(wv[c], ls[c-64]));
    float y = __fadd_rn(__fmul_rn(__fsub_rn(acc, mn), sc), bt);
    y = (y >= 0.f) ? y : __fmul_rn(0.2f, y);
    mx = fmaxf(mx, y);
  }
  pmax[wave*64 + lane] = mx;
  __syncthreads();
  if (tid < 64) {
    const float m01 = fmaxf(pmax[tid], pmax[64 + tid]);
    const float m23 = fmaxf(pmax[128 + tid], pmax[192 + tid]);
    const float m = fmaxf(m01, m23);
    outc[((size_t)(b*64 + tid))*NPTS + n] = m;
    hpm[(size_t)row*64 + tid] = m;
  }
}

// ---------------- fuse: hf = elu(fw . [h; reps]); + hnorm + packed-f16 copy ----------------
__global__ __launch_bounds__(256)
void fuse_kernel(const float* __restrict__ hpm, const float* __restrict__ repsL,
                 const float* __restrict__ fwtL, float* __restrict__ hf,
                 float* __restrict__ hnorm, uint4* __restrict__ hf16) {
#pragma clang fp contract(off)
  __shared__ float cs[32*130];   // 32 points x 128 channels (+2 pad)
  __shared__ float yb[32*65];    // fused outputs for the sq/f16 pass
  const int tid = threadIdx.x, wave = tid >> 6, lane = tid & 63;
  const size_t rowbase = (size_t)blockIdx.x*32;          // b*N + n0
  const int b = (int)(rowbase >> 13);
  const int n0 = (int)(rowbase & (NPTS-1));
#pragma unroll
  for (int j = 0; j < 8; ++j) {
    const int p = j*4 + wave;
    cs[p*130 + lane] = hpm[(rowbase + p)*64 + lane];
  }
  const float* rb = repsL + (size_t)b*64*NPTS;
  const int pl = lane & 31;
#pragma unroll
  for (int j = 0; j < 8; ++j) {
    const int c = j*8 + wave*2 + (lane >> 5);
    cs[pl*130 + 64 + c] = rb[(size_t)c*NPTS + n0 + pl];
  }
  __syncthreads();
  float wv[128];
#pragma unroll
  for (int c = 0; c < 128; ++c) wv[c] = fwtL[c*64 + lane];
  for (int pp = 0; pp < 8; ++pp) {
    const int p = wave*8 + pp;
    float acc = __fmul_rn(wv[0], cs[p*130]);
#pragma unroll
    for (int c = 1; c < 128; ++c)
      acc = __fadd_rn(acc, __fmul_rn(wv[c], cs[p*130 + c]));
    const float y = (acc > 0.f) ? acc : (float)expm1((double)acc);  // jax.nn.elu
    hf[(rowbase + p)*64 + lane] = y;
    yb[p*65 + lane] = y;
  }
  __syncthreads();
  if (tid < 32) {
    float a = __fmul_rn(yb[tid*65], yb[tid*65]);
#pragma unroll
    for (int c = 1; c < 64; ++c) {
      const float t = yb[tid*65 + c];
      a = __fadd_rn(a, __fmul_rn(t, t));
    }
    hnorm[rowbase + tid] = a;
  }
  // packed f16 copy: point p = tid>>3, chan group g = tid&7 (ch 8g..8g+7)
  {
    const int p = tid >> 3, g = tid & 7;
    const float* yp = &yb[p*65 + g*8];
    uint4 w;
    w.x = pk16(yp[0], yp[1]);
    w.y = pk16(yp[2], yp[3]);
    w.z = pk16(yp[4], yp[5]);
    w.w = pk16(yp[6], yp[7]);
    hf16[(rowbase + p)*8 + g] = w;
  }
}

// ---------------- launch ----------------
extern "C" void kernel_launch(void* const* d_in, const int* in_sizes, int n_in,
                              void* d_out, int out_size, void* d_ws, size_t ws_size,
                              hipStream_t stream) {
  const float* x    = (const float*)d_in[0];
  const float* reps = (const float*)d_in[1];
  const float* cw0  = (const float*)d_in[2];
  const float* cws  = (const float*)d_in[3];
  const float* gam  = (const float*)d_in[4];
  const float* bet  = (const float*)d_in[5];
  const float* rmn  = (const float*)d_in[6];
  const float* rvr  = (const float*)d_in[7];
  const float* fws  = (const float*)d_in[8];
  float* out = (float*)d_out;

  unsigned long long* cand = (unsigned long long*)d_ws;  // ROWS*16*16 u64 = 33.6MB
  uint4* hf16 = (uint4*)(cand + (size_t)ROWS*NSPLIT*KEEP); // ROWS*8 uint4 = 2MB
  int* idx = (int*)(hf16 + (size_t)ROWS*8);
  float* w = (float*)(idx + (size_t)ROWS*KNN);
  float* xt    = w;  w += (size_t)ROWS*4;
  float* xnorm = w;  w += ROWS;
  float* hf    = w;  w += (size_t)ROWS*64;
  float* hnorm = w;  w += ROWS;
  float* hpm   = w;  w += (size_t)ROWS*64;
  float* Wt0   = w;  w += 8*64;
  float* Wt    = w;  w += 3*128*64;
  float* fwt   = w;  w += 3*128*64;

  hipLaunchKernelGGL(prep_w0_kernel, dim3(1),   dim3(384), 0, stream, cw0, Wt0);
  hipLaunchKernelGGL(prep_wc_kernel, dim3(96),  dim3(256), 0, stream, cws, Wt);
  hipLaunchKernelGGL(prep_fw_kernel, dim3(96),  dim3(256), 0, stream, fws, fwt);
  hipLaunchKernelGGL(prep_x_kernel,  dim3(ROWS/256), dim3(256), 0, stream, x, xt, xnorm);

  const size_t chunk = (size_t)NB*64*NPTS;

  // layer 0
  hipLaunchKernelGGL(knn0_kernel,  dim3(ROWS/4), dim3(256), 0, stream, xt, xnorm, idx);
  hipLaunchKernelGGL(conv0_kernel, dim3(ROWS/4), dim3(256), 0, stream,
                     idx, xt, Wt0, gam, bet, rmn, rvr, out, hpm);

  for (int i = 0; i < 3; ++i) {
    hipLaunchKernelGGL(fuse_kernel, dim3(ROWS/32), dim3(256), 0, stream,
                       hpm, reps + (size_t)i*NB*64*NPTS, fwt + (size_t)i*8192, hf, hnorm, hf16);
    hipLaunchKernelGGL(knn64_scan_kernel,  dim3((ROWS/256)*NSPLIT), dim3(256), 0, stream,
                       hf16, hnorm, cand);
    hipLaunchKernelGGL(knn64_select_kernel, dim3(ROWS/4), dim3(256), 0, stream,
                       hf, hnorm, cand, idx);
    hipLaunchKernelGGL(convL_kernel, dim3(ROWS), dim3(256), 0, stream,
                       idx, hf, Wt + (size_t)i*8192, gam, bet, rmn, rvr, i + 1,
                       out + (size_t)(i+1)*chunk, hpm);
  }
}

// Round 12
// 2261.701 us; speedup vs baseline: 15.4377x; 1.3583x over previous
//
#include <hip/hip_runtime.h>
#include <math.h>

#define NPTS 8192
#define NB 2
#define KNN 20
#define ROWS (NB*NPTS)    // 16384
#define NSPLIT 16         // candidate-range splits per row (knn64)
#define CPS (NPTS/NSPLIT) // 512 candidates per scanner
#define KEEP 12           // approx top-KEEP per (row,split), packed u32
#define NC 64             // survivors refined with exact np keys (1/lane)
#define TILE 128          // candidates staged per LDS tile (f16: 16 KB)

typedef _Float16 half2v __attribute__((ext_vector_type(2)));

// Reference-replication rules (np/XLA fp32), used ONLY in refine stages:
//   inner[n,m] = sequential-c FMA chain (first term = rounded mul)
//   sq[n]      = sequential-c adds of ROUNDED squares (no FMA)
//   key        = (2.0f*inner - sq_n) - sq_m, all fp32
//   top-20     = stable (value desc, index asc)
// Prefilter keys are approx (f16 dot / trunc-19): recall-only, never ranking.

__device__ __forceinline__ unsigned long long shfl_xor_u64(unsigned long long v, int m) {
  unsigned lo = (unsigned)__shfl_xor((int)(unsigned)(v & 0xFFFFFFFFull), m, 64);
  unsigned hi = (unsigned)__shfl_xor((int)(unsigned)(v >> 32), m, 64);
  return ((unsigned long long)hi << 32) | (unsigned long long)lo;
}

__device__ __forceinline__ unsigned long long packkey(float negd, int m) {
  unsigned nb = __float_as_uint(negd) ^ 0x80000000u;            // exact negation
  nb = (nb & 0x80000000u) ? ~nb : (nb | 0x80000000u);           // monotone asc map
  return ((unsigned long long)nb << 32) | (unsigned)m;
}

// u32 sortable: ascending u32 == distance ascending (negd descending)
__device__ __forceinline__ unsigned sortdesc32(float negd) {
  unsigned s = __float_as_uint(negd);
  s = (s & 0x80000000u) ? (s ^ 0xFFFFFFFFu) : (s | 0x80000000u);
  return ~s;
}
// pack trunc-19-bit key + 13-bit candidate idx into one sortable u32
__device__ __forceinline__ unsigned pk32(float negd, int m) {
  return (sortdesc32(negd) & 0xFFFFE000u) | (unsigned)m;
}

__device__ __forceinline__ half2v u2h(unsigned u) {
  half2v h; __builtin_memcpy(&h, &u, 4); return h;
}
__device__ __forceinline__ unsigned pk16(float a, float b) {
  const auto h = __builtin_amdgcn_cvt_pkrtz(a, b);   // v2 fp16, RTZ
  unsigned u; __builtin_memcpy(&u, &h, 4); return u;
}

// ---------------- prep ----------------

__global__ void prep_w0_kernel(const float* __restrict__ cw0, float* __restrict__ Wt0) {
  const int tid = threadIdx.x;                 // 384 threads
  const int c = tid >> 6, o = tid & 63;
  if (tid < 384) Wt0[c*64 + o] = cw0[o*6 + c];
}

__global__ void prep_wc_kernel(const float* __restrict__ cws, float* __restrict__ Wt) {
  const int f = blockIdx.x*256 + threadIdx.x;  // < 3*8192
  const int i = f >> 13, r = f & 8191, c = r >> 6, o = r & 63;
  Wt[f] = cws[i*8192 + o*128 + c];
}

__global__ void prep_fw_kernel(const float* __restrict__ fws, float* __restrict__ fwt) {
  const int f = blockIdx.x*256 + threadIdx.x;  // < 3*8192
  const int i = f >> 13, r = f & 8191, c = r >> 6, o = r & 63;
  fwt[f] = fws[i*8192 + o*128 + c];
}

__global__ void prep_x_kernel(const float* __restrict__ x,
                              float* __restrict__ xt, float* __restrict__ xnorm) {
#pragma clang fp contract(off)
  const int t = blockIdx.x*256 + threadIdx.x;  // < ROWS
  const int b = t >> 13, n = t & (NPTS-1);
  const float v0 = x[((size_t)b*3 + 0)*NPTS + n];
  const float v1 = x[((size_t)b*3 + 1)*NPTS + n];
  const float v2 = x[((size_t)b*3 + 2)*NPTS + n];
  ((float4*)xt)[t] = make_float4(v0, v1, v2, 0.f);
  float a = __fmul_rn(v0, v0);
  a = __fadd_rn(a, __fmul_rn(v1, v1));
  a = __fadd_rn(a, __fmul_rn(v2, v2));
  xnorm[t] = a;
}

// ---------------- KNN layer 0: packed-u32 prefilter + np-exact refine ----------------
__global__ __launch_bounds__(256)
void knn0_kernel(const float* __restrict__ pts, const float* __restrict__ norms,
                 int* __restrict__ idx) {
#pragma clang fp contract(off)
  const int tid = threadIdx.x;
  const int wave = tid >> 6, lane = tid & 63;
  const int row = blockIdx.x*4 + wave;
  const int b = row >> 13, n = row & (NPTS-1);
  const float4* P = ((const float4*)pts) + (size_t)b * NPTS;
  const float4 rv = P[n];
  const float* nrm = norms + (size_t)b*NPTS;
  const float nrmN = nrm[n];

  unsigned keys[KEEP];
#pragma unroll
  for (int i = 0; i < KEEP; ++i) keys[i] = 0xFFFFFFFFu;

  for (int t = 0; t < NPTS/64; ++t) {
    const int m = t*64 + lane;
    const float4 q = P[m];
    float acc = __fmul_rn(rv.x, q.x);
    acc = fmaf(rv.y, q.y, acc);
    acc = fmaf(rv.z, q.z, acc);
    const float negd = __fsub_rn(__fsub_rn(__fmul_rn(2.0f, acc), nrmN), nrm[m]);
    unsigned ck = pk32(negd, m);
#pragma unroll
    for (int i = 0; i < KEEP; ++i) {       // min/max sorted-insert, 2 VALU/slot
      const unsigned lo = min(ck, keys[i]);
      const unsigned hi = max(ck, keys[i]);
      keys[i] = lo; ck = hi;
    }
  }

  // pop-merge approx-top-64 (one per lane)
  int cidx = 0;
  for (int r = 0; r < NC; ++r) {
    unsigned best = keys[0];
#pragma unroll
    for (int off = 32; off; off >>= 1) best = min(best, (unsigned)__shfl_xor((int)best, off, 64));
    if (keys[0] == best) {
#pragma unroll
      for (int i = 0; i < KEEP-1; ++i) keys[i] = keys[i+1];
      keys[KEEP-1] = 0xFFFFFFFFu;
    }
    if (lane == r) cidx = (int)(best & 0x1FFFu);
  }

  // np-exact key per lane
  unsigned long long uk;
  {
    const float4 q = P[cidx];
    float acc = __fmul_rn(rv.x, q.x);
    acc = fmaf(rv.y, q.y, acc);
    acc = fmaf(rv.z, q.z, acc);
    const float negd = __fsub_rn(__fsub_rn(__fmul_rn(2.0f, acc), nrmN), nrm[cidx]);
    uk = packkey(negd, cidx);
  }
  int stash = 0;
  for (int r = 0; r < KNN; ++r) {
    unsigned long long best = uk;
#pragma unroll
    for (int off = 32; off; off >>= 1) {
      const unsigned long long o = shfl_xor_u64(best, off);
      if (o < best) best = o;
    }
    if (lane == r) stash = (int)(unsigned)(best & 0xFFFFFFFFull);
    if (uk == best) uk = ~0ull;
  }
  if (lane < KNN) idx[(size_t)row*KNN + lane] = stash;
}

// ---------------- KNN 1-3 pass 1: fp16-dot2 scan, packed-u32 min/max reservoir ----------------
__global__ __launch_bounds__(256, 4)
void knn64_scan_kernel(const uint4* __restrict__ hf16, const float* __restrict__ norms,
                       unsigned* __restrict__ cand) {
  __shared__ uint4 tq[TILE*8];     // 128 cands x 64ch f16 = 1024 uint4 = 16 KB
  __shared__ float tnrm[TILE];
  const int tid = threadIdx.x;
  const int rb = blockIdx.x >> 4, cs = blockIdx.x & (NSPLIT-1);
  const int row = rb*256 + tid;          // 256 consecutive rows; same batch
  const int b = row >> 13;
  const int csBase = cs*CPS;

  half2v f2[32];                         // 64 ch f16 = 32 VGPRs
  {
    const uint4* Pf = hf16 + (size_t)row*8;
#pragma unroll
    for (int u = 0; u < 8; ++u) {
      const uint4 q = Pf[u];
      f2[u*4+0] = u2h(q.x); f2[u*4+1] = u2h(q.y);
      f2[u*4+2] = u2h(q.z); f2[u*4+3] = u2h(q.w);
    }
  }
  const float nrmN = norms[row];
  const float* nrmC = norms + (size_t)b*NPTS + csBase;
  const uint4* Pc = hf16 + ((size_t)b*NPTS + csBase)*8;

  unsigned keys[KEEP];
#pragma unroll
  for (int i = 0; i < KEEP; ++i) keys[i] = 0xFFFFFFFFu;

  for (int t = 0; t < CPS/TILE; ++t) {
#pragma unroll
    for (int j = 0; j < 4; ++j)
      tq[tid + j*256] = Pc[(size_t)t*(TILE*8) + tid + j*256];
    if (tid < TILE) tnrm[tid] = nrmC[t*TILE + tid];
    __syncthreads();

    for (int jj = 0; jj < TILE; ++jj) {
      const uint4* qp = &tq[jj*8];   // wave-uniform -> broadcast ds_read_b128
      float a0 = 0.f, a1 = 0.f, a2 = 0.f, a3 = 0.f;
#pragma unroll
      for (int u = 0; u < 8; ++u) {
        const uint4 q = qp[u];
        a0 = __builtin_amdgcn_fdot2(f2[u*4+0], u2h(q.x), a0, false);
        a1 = __builtin_amdgcn_fdot2(f2[u*4+1], u2h(q.y), a1, false);
        a2 = __builtin_amdgcn_fdot2(f2[u*4+2], u2h(q.z), a2, false);
        a3 = __builtin_amdgcn_fdot2(f2[u*4+3], u2h(q.w), a3, false);
      }
      const float inner = (a0 + a1) + (a2 + a3);
      const float negd = 2.0f*inner - nrmN - tnrm[jj];
      unsigned ck = pk32(negd, csBase + t*TILE + jj);
#pragma unroll
      for (int i = 0; i < KEEP; ++i) {   // unconditional min/max chain
        const unsigned lo = min(ck, keys[i]);
        const unsigned hi = max(ck, keys[i]);
        keys[i] = lo; ck = hi;
      }
    }
    __syncthreads();
  }

  unsigned* o = cand + ((size_t)row*NSPLIT + cs)*KEEP;
#pragma unroll
  for (int i = 0; i < KEEP; ++i) o[i] = keys[i];   // ascending (sorted)
}

// ---------------- KNN 1-3 pass 2: merge 192 -> top-64 approx -> np-exact top-20 ----------------
__global__ __launch_bounds__(256)
void knn64_select_kernel(const float* __restrict__ hf, const float* __restrict__ norms,
                         const unsigned* __restrict__ cand, int* __restrict__ idx) {
#pragma clang fp contract(off)
  const int tid = threadIdx.x, wave = tid >> 6, lane = tid & 63;
  const int row = blockIdx.x*4 + wave;
  const int b = row >> 13;
  const unsigned* cr = cand + (size_t)row*(NSPLIT*KEEP);
  // lane holds 3 consecutive of one split's sorted-12 (12%3==0): ascending
  unsigned a0 = cr[lane*3 + 0];
  unsigned a1 = cr[lane*3 + 1];
  unsigned a2 = cr[lane*3 + 2];

  int cidx = 0;
  for (int r = 0; r < NC; ++r) {
    unsigned best = a0;
#pragma unroll
    for (int off = 32; off; off >>= 1) best = min(best, (unsigned)__shfl_xor((int)best, off, 64));
    if (a0 == best) { a0 = a1; a1 = a2; a2 = 0xFFFFFFFFu; }
    if (lane == r) cidx = (int)(best & 0x1FFFu);
  }

  // np-exact key for each lane's survivor
  unsigned long long uk;
  {
    const float4* Pr = ((const float4*)hf) + (size_t)row*16;
    const float4* Pc = ((const float4*)hf) + ((size_t)b*NPTS + cidx)*16;
    float4 fr = Pr[0], qc = Pc[0];
    float acc = __fmul_rn(fr.x, qc.x);
    acc = fmaf(fr.y, qc.y, acc);
    acc = fmaf(fr.z, qc.z, acc);
    acc = fmaf(fr.w, qc.w, acc);
#pragma unroll
    for (int i = 1; i < 16; ++i) {
      fr = Pr[i]; qc = Pc[i];
      acc = fmaf(fr.x, qc.x, acc);
      acc = fmaf(fr.y, qc.y, acc);
      acc = fmaf(fr.z, qc.z, acc);
      acc = fmaf(fr.w, qc.w, acc);
    }
    const float negd = __fsub_rn(__fsub_rn(__fmul_rn(2.0f, acc), norms[row]),
                                 norms[(size_t)b*NPTS + cidx]);
    uk = packkey(negd, cidx);
  }

  int stash = 0;
  for (int r = 0; r < KNN; ++r) {
    unsigned long long best = uk;
#pragma unroll
    for (int off = 32; off; off >>= 1) {
      const unsigned long long o = shfl_xor_u64(best, off);
      if (o < best) best = o;
    }
    if (lane == r) stash = (int)(unsigned)(best & 0xFFFFFFFFull);
    if (uk == best) uk = ~0ull;   // unique keys: exactly one lane retires
  }
  if (lane < KNN) idx[(size_t)row*KNN + lane] = stash;
}

// ---------------- conv layer 0 ----------------
__global__ __launch_bounds__(256)
void conv0_kernel(const int* __restrict__ idx, const float* __restrict__ xt,
                  const float* __restrict__ Wt0, const float* __restrict__ gam,
                  const float* __restrict__ bet, const float* __restrict__ rmn,
                  const float* __restrict__ rvr,
                  float* __restrict__ outc, float* __restrict__ hpm) {
#pragma clang fp contract(off)
  const int tid = threadIdx.x, wave = tid >> 6, lane = tid & 63;
  const int row = blockIdx.x*4 + wave;
  const int b = row >> 13, n = row & (NPTS-1);
  const float4* P = ((const float4*)xt) + (size_t)b * NPTS;
  const float4 ctr = P[n];
  float wv[6];
#pragma unroll
  for (int c = 0; c < 6; ++c) wv[c] = Wt0[c*64 + lane];
  const float sc = __fdiv_rn(gam[lane], sqrtf(__fadd_rn(rvr[lane], 1e-5f)));
  const float mn = rmn[lane], bt = bet[lane];

  float mx = -3.0e38f;
  const int* ip = idx + (size_t)row*KNN;
  for (int k = 0; k < KNN; ++k) {
    const float4 q = P[ip[k]];
    float acc = __fmul_rn(wv[0], __fsub_rn(q.x, ctr.x));
    acc = __fadd_rn(acc, __fmul_rn(wv[1], __fsub_rn(q.y, ctr.y)));
    acc = __fadd_rn(acc, __fmul_rn(wv[2], __fsub_rn(q.z, ctr.z)));
    acc = __fadd_rn(acc, __fmul_rn(wv[3], ctr.x));
    acc = __fadd_rn(acc, __fmul_rn(wv[4], ctr.y));
    acc = __fadd_rn(acc, __fmul_rn(wv[5], ctr.z));
    float y = __fadd_rn(__fmul_rn(__fsub_rn(acc, mn), sc), bt);
    y = (y >= 0.f) ? y : __fmul_rn(0.2f, y);
    mx = fmaxf(mx, y);
  }
  outc[((size_t)(b*64 + lane))*NPTS + n] = mx;
  hpm[(size_t)row*64 + lane] = mx;
}

// ---------------- conv layers 1-3 ----------------
__global__ __launch_bounds__(256)
void convL_kernel(const int* __restrict__ idx, const float* __restrict__ hf,
                  const float* __restrict__ WtL, const float* __restrict__ gam,
                  const float* __restrict__ bet, const float* __restrict__ rmn,
                  const float* __restrict__ rvr, const int L,
                  float* __restrict__ outc, float* __restrict__ hpm) {
#pragma clang fp contract(off)
  __shared__ float ls[21*64];          // row 0 = ctr, rows 1..20 = neighbors
  __shared__ float pmax[4*64];
  const int tid = threadIdx.x, wave = tid >> 6, lane = tid & 63;
  const int row = blockIdx.x;
  const int b = row >> 13, n = row & (NPTS-1);
  const int* ip = idx + (size_t)row*KNN;
#pragma unroll
  for (int j = 0; j < 6; ++j) {
    const int r = j*4 + wave;
    if (r < 21) {
      const int src = (r == 0) ? row : (b*NPTS + ip[r-1]);
      ls[r*64 + lane] = hf[(size_t)src*64 + lane];
    }
  }
  __syncthreads();

  float wv[128];
#pragma unroll
  for (int c = 0; c < 128; ++c) wv[c] = WtL[c*64 + lane];
  const float sc = __fdiv_rn(gam[L*64 + lane], sqrtf(__fadd_rn(rvr[L*64 + lane], 1e-5f)));
  const float mn = rmn[L*64 + lane], bt = bet[L*64 + lane];

  float mx = -3.0e38f;
  for (int j = 0; j < 5; ++j) {
    const int k = wave*5 + j;
    const float* nb = &ls[(1+k)*64];
    float acc = __fmul_rn(wv[0], __fsub_rn(nb[0], ls[0]));
#pragma unroll
    for (int c = 1; c < 64; ++c)
      acc = __fadd_rn(acc, __fmul_rn(wv[c], __fsub_rn(nb[c], ls[c])));
#pragma unroll
    for (int c = 64; c < 128; ++c)
      acc = __fadd_rn(acc, __fmul_rn(wv[c], ls[c-64]));
    float y = __fadd_rn(__fmul_rn(__fsub_rn(acc, mn), sc), bt);
    y = (y >= 0.f) ? y : __fmul_rn(0.2f, y);
    mx = fmaxf(mx, y);
  }
  pmax[wave*64 + lane] = mx;
  __syncthreads();
  if (tid < 64) {
    const float m01 = fmaxf(pmax[tid], pmax[64 + tid]);
    const float m23 = fmaxf(pmax[128 + tid], pmax[192 + tid]);
    const float m = fmaxf(m01, m23);
    outc[((size_t)(b*64 + tid))*NPTS + n] = m;
    hpm[(size_t)row*64 + tid] = m;
  }
}

// ---------------- fuse: hf = elu(fw . [h; reps]); + hnorm + packed-f16 copy ----------------
__global__ __launch_bounds__(256)
void fuse_kernel(const float* __restrict__ hpm, const float* __restrict__ repsL,
                 const float* __restrict__ fwtL, float* __restrict__ hf,
                 float* __restrict__ hnorm, uint4* __restrict__ hf16) {
#pragma clang fp contract(off)
  __shared__ float cs[32*130];   // 32 points x 128 channels (+2 pad)
  __shared__ float yb[32*65];    // fused outputs for the sq/f16 pass
  const int tid = threadIdx.x, wave = tid >> 6, lane = tid & 63;
  const size_t rowbase = (size_t)blockIdx.x*32;          // b*N + n0
  const int b = (int)(rowbase >> 13);
  const int n0 = (int)(rowbase & (NPTS-1));
#pragma unroll
  for (int j = 0; j < 8; ++j) {
    const int p = j*4 + wave;
    cs[p*130 + lane] = hpm[(rowbase + p)*64 + lane];
  }
  const float* rb = repsL + (size_t)b*64*NPTS;
  const int pl = lane & 31;
#pragma unroll
  for (int j = 0; j < 8; ++j) {
    const int c = j*8 + wave*2 + (lane >> 5);
    cs[pl*130 + 64 + c] = rb[(size_t)c*NPTS + n0 + pl];
  }
  __syncthreads();
  float wv[128];
#pragma unroll
  for (int c = 0; c < 128; ++c) wv[c] = fwtL[c*64 + lane];
  for (int pp = 0; pp < 8; ++pp) {
    const int p = wave*8 + pp;
    float acc = __fmul_rn(wv[0], cs[p*130]);
#pragma unroll
    for (int c = 1; c < 128; ++c)
      acc = __fadd_rn(acc, __fmul_rn(wv[c], cs[p*130 + c]));
    const float y = (acc > 0.f) ? acc : (float)expm1((double)acc);  // jax.nn.elu
    hf[(rowbase + p)*64 + lane] = y;
    yb[p*65 + lane] = y;
  }
  __syncthreads();
  if (tid < 32) {
    float a = __fmul_rn(yb[tid*65], yb[tid*65]);
#pragma unroll
    for (int c = 1; c < 64; ++c) {
      const float t = yb[tid*65 + c];
      a = __fadd_rn(a, __fmul_rn(t, t));
    }
    hnorm[rowbase + tid] = a;
  }
  {
    const int p = tid >> 3, g = tid & 7;
    const float* yp = &yb[p*65 + g*8];
    uint4 w;
    w.x = pk16(yp[0], yp[1]);
    w.y = pk16(yp[2], yp[3]);
    w.z = pk16(yp[4], yp[5]);
    w.w = pk16(yp[6], yp[7]);
    hf16[(rowbase + p)*8 + g] = w;
  }
}

// ---------------- launch ----------------
extern "C" void kernel_launch(void* const* d_in, const int* in_sizes, int n_in,
                              void* d_out, int out_size, void* d_ws, size_t ws_size,
                              hipStream_t stream) {
  const float* x    = (const float*)d_in[0];
  const float* reps = (const float*)d_in[1];
  const float* cw0  = (const float*)d_in[2];
  const float* cws  = (const float*)d_in[3];
  const float* gam  = (const float*)d_in[4];
  const float* bet  = (const float*)d_in[5];
  const float* rmn  = (const float*)d_in[6];
  const float* rvr  = (const float*)d_in[7];
  const float* fws  = (const float*)d_in[8];
  float* out = (float*)d_out;

  unsigned* cand = (unsigned*)d_ws;                       // ROWS*16*12 u32 = 12.6MB
  uint4* hf16 = (uint4*)(cand + (size_t)ROWS*NSPLIT*KEEP);// ROWS*8 uint4 = 2MB
  int* idx = (int*)(hf16 + (size_t)ROWS*8);
  float* w = (float*)(idx + (size_t)ROWS*KNN);
  float* xt    = w;  w += (size_t)ROWS*4;
  float* xnorm = w;  w += ROWS;
  float* hf    = w;  w += (size_t)ROWS*64;
  float* hnorm = w;  w += ROWS;
  float* hpm   = w;  w += (size_t)ROWS*64;
  float* Wt0   = w;  w += 8*64;
  float* Wt    = w;  w += 3*128*64;
  float* fwt   = w;  w += 3*128*64;

  hipLaunchKernelGGL(prep_w0_kernel, dim3(1),   dim3(384), 0, stream, cw0, Wt0);
  hipLaunchKernelGGL(prep_wc_kernel, dim3(96),  dim3(256), 0, stream, cws, Wt);
  hipLaunchKernelGGL(prep_fw_kernel, dim3(96),  dim3(256), 0, stream, fws, fwt);
  hipLaunchKernelGGL(prep_x_kernel,  dim3(ROWS/256), dim3(256), 0, stream, x, xt, xnorm);

  const size_t chunk = (size_t)NB*64*NPTS;

  // layer 0
  hipLaunchKernelGGL(knn0_kernel,  dim3(ROWS/4), dim3(256), 0, stream, xt, xnorm, idx);
  hipLaunchKernelGGL(conv0_kernel, dim3(ROWS/4), dim3(256), 0, stream,
                     idx, xt, Wt0, gam, bet, rmn, rvr, out, hpm);

  for (int i = 0; i < 3; ++i) {
    hipLaunchKernelGGL(fuse_kernel, dim3(ROWS/32), dim3(256), 0, stream,
                       hpm, reps + (size_t)i*NB*64*NPTS, fwt + (size_t)i*8192, hf, hnorm, hf16);
    hipLaunchKernelGGL(knn64_scan_kernel,  dim3((ROWS/256)*NSPLIT), dim3(256), 0, stream,
                       hf16, hnorm, cand);
    hipLaunchKernelGGL(knn64_select_kernel, dim3(ROWS/4), dim3(256), 0, stream,
                       hf, hnorm, cand, idx);
    hipLaunchKernelGGL(convL_kernel, dim3(ROWS), dim3(256), 0, stream,
                       idx, hf, Wt + (size_t)i*8192, gam, bet, rmn, rvr, i + 1,
                       out + (size_t)(i+1)*chunk, hpm);
  }
}